// Round 6
// baseline (737.775 us; speedup 1.0000x reference)
//
#include <hip/hip_runtime.h>

// ---------------- problem constants ----------------
constexpr int B_SZ = 2, LSEQ = 2048, D_MODEL = 2048;
constexpr int D_SSM = 4096, D_STATE = 128, NHEADS = 64, HEADDIM = 64;
constexpr int CHUNK = 128;
constexpr int NCH = LSEQ / CHUNK;             // 16
constexpr int BL = B_SZ * LSEQ;               // 4096 token rows
constexpr int DIN = 2 * D_SSM + 2 * D_STATE + NHEADS; // 8512
constexpr int DINP = 8576;                    // padded to 67*128
constexpr int CONVDIM = D_SSM + 2 * D_STATE;  // 4352
constexpr int BOFF = D_SSM;                   // B offset inside xBC_conv
constexpr int COFF = D_SSM + D_STATE;         // C offset inside xBC_conv

// ---------------- workspace layout (bytes) — total ~218 MiB ----------------
constexpr size_t OFF_WIN = 0;                                      // W_in bf16 -> later y bf16
constexpr size_t OFF_UB  = OFF_WIN + (size_t)DINP * D_MODEL * 2;   // u bf16 -> later W_out bf16
constexpr size_t OFF_ZX  = OFF_UB + (size_t)BL * D_MODEL * 2;      // zxbcdt bf16 (BL x DINP)
constexpr size_t OFF_XBC = OFF_ZX + (size_t)BL * DINP * 2;         // conv output bf16 (BL x 4352)
constexpr size_t OFF_DT  = OFF_XBC + (size_t)BL * CONVDIM * 2;     // dt fp32 (BL x 64)
constexpr size_t OFF_ST  = OFF_DT + (size_t)BL * NHEADS * 4;       // states fp32 (2048 x 8192), reused as Y
constexpr size_t OFF_CB  = OFF_ST + (size_t)B_SZ * NCH * NHEADS * HEADDIM * D_STATE * 4;
constexpr size_t OFF_DAS = OFF_CB + (size_t)B_SZ * NCH * CHUNK * CHUNK * 4;
constexpr size_t WS_NEED = OFF_DAS + (size_t)B_SZ * NCH * NHEADS * 4 + 4096;

typedef float f32x4 __attribute__((ext_vector_type(4)));
typedef __bf16 bf16x8 __attribute__((ext_vector_type(8)));

__device__ __forceinline__ unsigned short f2bf(float f) {
  unsigned int x = __float_as_uint(f);
  x += 0x7fffu + ((x >> 16) & 1u);   // round-to-nearest-even
  return (unsigned short)(x >> 16);
}
__device__ __forceinline__ float bf2f(unsigned short u) {
  return __uint_as_float(((unsigned int)u) << 16);
}

// async global->LDS, 16 B per lane; LDS dest = wave-uniform base + lane*16
__device__ __forceinline__ void llds16(const unsigned short* g, unsigned short* l) {
  __builtin_amdgcn_global_load_lds(
      (const __attribute__((address_space(1))) unsigned int*)g,
      (__attribute__((address_space(3))) unsigned int*)l, 16, 0, 0);
}

// ---------------- fp32 -> bf16 converts ----------------
// fused u + W_in (W_in zero-padded 4358144 -> 4390912 float4s)
__global__ void k_cvt_uw(const float4* __restrict__ u, ushort4* __restrict__ ub,
                         const float4* __restrict__ wi, ushort4* __restrict__ winb) {
  int i = blockIdx.x * 256 + threadIdx.x;
  if (i < 2097152) {
    float4 v = u[i];
    ushort4 o; o.x = f2bf(v.x); o.y = f2bf(v.y); o.z = f2bf(v.z); o.w = f2bf(v.w);
    ub[i] = o;
  } else {
    int j = i - 2097152;
    if (j >= 4390912) return;
    float4 v = make_float4(0.f, 0.f, 0.f, 0.f);
    if (j < 4358144) v = wi[j];
    ushort4 o; o.x = f2bf(v.x); o.y = f2bf(v.y); o.z = f2bf(v.z); o.w = f2bf(v.w);
    winb[j] = o;
  }
}

__global__ void k_cvt4(const float4* __restrict__ src, ushort4* __restrict__ dst,
                       int n4, int nsrc4) {
  int i = blockIdx.x * 256 + threadIdx.x;
  if (i >= n4) return;
  float4 v = make_float4(0.f, 0.f, 0.f, 0.f);
  if (i < nsrc4) v = src[i];
  ushort4 o;
  o.x = f2bf(v.x); o.y = f2bf(v.y); o.z = f2bf(v.z); o.w = f2bf(v.w);
  dst[i] = o;
}

// ---------------- bf16 MFMA GEMM: C[M][N] = A[M][K] * B[N][K]^T ----------------
// 128x128 tile, 4 waves, BK=32, async global_load_lds staging,
// single-barrier double-buffered K-loop, XOR k-chunk LDS swizzle,
// panel-swizzled 1D grid (8 N-tiles/panel, M innermost) for L2 reuse.
template <bool OUT_BF16>
__global__ __launch_bounds__(256, 2) void k_gemm_bt(
    const unsigned short* __restrict__ A, const unsigned short* __restrict__ Bm,
    void* __restrict__ Cv, int M, int N, int K) {
  __shared__ __align__(16) unsigned short As[2][128 * 32];
  __shared__ __align__(16) unsigned short Bs[2][128 * 32];
  int t = threadIdx.x;
  int mt = M >> 7, ntl = N >> 7;
  int bid = blockIdx.x;
  int panel = bid / (8 * mt);
  int within = bid - panel * 8 * mt;
  int pw = min(8, ntl - panel * 8);
  int m0 = (within / pw) * 128;
  int n0 = (panel * 8 + within % pw) * 128;
  int w = t >> 6, lane = t & 63;
  int wm = (w >> 1) * 64, wn = (w & 1) * 64;
  int lr = lane & 15;
  f32x4 acc[4][4] = {};
  // staging: thread t -> rows sr,sr+64, LDS slot t&3 at elem 8t (lane*16B).
  // slot s holds global k-chunk c = s ^ swz(r), swz(r)=(r&3)^((r>>2)&3).
  int sr = t >> 2;
  int swzS = ((sr & 3) ^ ((sr >> 2) & 3));
  int cSrc = ((t & 3) ^ swzS) * 8;
  const unsigned short* Ap = A + (size_t)(m0 + sr) * K + cSrc;
  const unsigned short* Bp = Bm + (size_t)(n0 + sr) * K + cSrc;
  int wb = w * 512;
  // prologue: stage k-chunk 0 into buffer 0
  llds16(Ap, As[0] + wb);
  llds16(Ap + (size_t)64 * K, As[0] + 2048 + wb);
  llds16(Bp, Bs[0] + wb);
  llds16(Bp + (size_t)64 * K, Bs[0] + 2048 + wb);
  int rsel = lane >> 4;
  int cur = 0;
  for (int k0 = 0; k0 < K; k0 += 32) {
    __syncthreads();   // drains in-flight loads -> buf cur ready; prev reads of buf cur^1 done
    if (k0 + 32 < K) {
      llds16(Ap + k0 + 32, As[cur ^ 1] + wb);
      llds16(Ap + (size_t)64 * K + k0 + 32, As[cur ^ 1] + 2048 + wb);
      llds16(Bp + k0 + 32, Bs[cur ^ 1] + wb);
      llds16(Bp + (size_t)64 * K + k0 + 32, Bs[cur ^ 1] + 2048 + wb);
    }
    const unsigned short* Ac = As[cur];
    const unsigned short* Bc = Bs[cur];
    bf16x8 af[4], bfv[4];
#pragma unroll
    for (int i = 0; i < 4; i++) {
      int row = wm + i * 16 + lr;
      int slot = rsel ^ ((row & 3) ^ ((row >> 2) & 3));
      af[i] = *(const bf16x8*)&Ac[row * 32 + slot * 8];
    }
#pragma unroll
    for (int i = 0; i < 4; i++) {
      int row = wn + i * 16 + lr;
      int slot = rsel ^ ((row & 3) ^ ((row >> 2) & 3));
      bfv[i] = *(const bf16x8*)&Bc[row * 32 + slot * 8];
    }
#pragma unroll
    for (int mi = 0; mi < 4; mi++)
#pragma unroll
      for (int ni = 0; ni < 4; ni++)
        acc[mi][ni] = __builtin_amdgcn_mfma_f32_16x16x32_bf16(af[mi], bfv[ni], acc[mi][ni], 0, 0, 0);
    cur ^= 1;
  }
  int orow = (lane >> 4) * 4, ocol = lane & 15;
#pragma unroll
  for (int mi = 0; mi < 4; mi++)
#pragma unroll
    for (int ni = 0; ni < 4; ni++) {
      int r0 = m0 + wm + mi * 16 + orow;
      int c0 = n0 + wn + ni * 16 + ocol;
#pragma unroll
      for (int r = 0; r < 4; r++) {
        if (OUT_BF16)
          ((unsigned short*)Cv)[(size_t)(r0 + r) * N + c0] = f2bf(acc[mi][ni][r]);
        else
          ((float*)Cv)[(size_t)(r0 + r) * N + c0] = acc[mi][ni][r];
      }
    }
}

// ---------------- dt = softplus(raw + dt_bias) (precise exp: feeds exponentials) ----------------
__global__ void k_dt(const unsigned short* __restrict__ zx, const float* __restrict__ dt_bias,
                     float* __restrict__ dt) {
  int id = blockIdx.x * 256 + threadIdx.x;   // BL*64
  int row = id >> 6, h = id & 63;
  float x = bf2f(zx[(size_t)row * DINP + (2 * D_SSM + 2 * D_STATE) + h]) + dt_bias[h];
  dt[id] = (x > 20.f) ? x : log1pf(expf(x));
}

// ---------------- causal depthwise conv (width 3) + bias + SiLU, 8 ch/thread ----------------
__global__ void k_conv(const unsigned short* __restrict__ zx, const float* __restrict__ cw,
                       const float* __restrict__ cbv, unsigned short* __restrict__ out) {
  constexpr int C8 = CONVDIM / 8;  // 544
  int id = blockIdx.x * 256 + threadIdx.x;
  if (id >= BL * C8) return;
  int c8 = id % C8;
  int row = id / C8;
  int b = row >> 11, l = row & 2047;
  int c0 = c8 * 8;
  float acc[8];
#pragma unroll
  for (int j = 0; j < 8; j++) acc[j] = cbv[c0 + j];
#pragma unroll
  for (int k = 0; k < 3; k++) {
    int ls = l + k - 2;
    if (ls < 0) continue;
    const unsigned short* src = zx + (size_t)(b * LSEQ + ls) * DINP + D_SSM + c0;
    ushort4 v0 = *(const ushort4*)src;
    ushort4 v1 = *(const ushort4*)(src + 4);
    float xv[8] = {bf2f(v0.x), bf2f(v0.y), bf2f(v0.z), bf2f(v0.w),
                   bf2f(v1.x), bf2f(v1.y), bf2f(v1.z), bf2f(v1.w)};
#pragma unroll
    for (int j = 0; j < 8; j++) acc[j] += xv[j] * cw[(c0 + j) * 3 + k];
  }
  ushort4 o0, o1;
  float s[8];
#pragma unroll
  for (int j = 0; j < 8; j++) s[j] = acc[j] / (1.f + __expf(-acc[j]));
  o0.x = f2bf(s[0]); o0.y = f2bf(s[1]); o0.z = f2bf(s[2]); o0.w = f2bf(s[3]);
  o1.x = f2bf(s[4]); o1.y = f2bf(s[5]); o1.z = f2bf(s[6]); o1.w = f2bf(s[7]);
  unsigned short* dst = out + (size_t)row * CONVDIM + c0;
  *(ushort4*)dst = o0;
  *(ushort4*)(dst + 4) = o1;
}

// ---------------- CB[l][s] = C[l] . B[s]  per (b,c) chunk (head-independent) ----------------
__global__ __launch_bounds__(256) void k_cb(const unsigned short* __restrict__ xBC,
                                            float* __restrict__ cbuf) {
  int bc = blockIdx.x;          // b*16 + c
  int row0 = bc * CHUNK;
  int t = threadIdx.x;
  __shared__ float Cs[32 * 132];
  int s = t & 127, lh = t >> 7; // lh in {0,1}
  for (int lt = 0; lt < 4; lt++) {
    __syncthreads();
    for (int i = t; i < 32 * 128; i += 256) {
      int l = i >> 7, n = i & 127;
      Cs[l * 132 + n] = bf2f(xBC[(size_t)(row0 + lt * 32 + l) * CONVDIM + COFF + n]);
    }
    __syncthreads();
    float acc[16];
#pragma unroll
    for (int j = 0; j < 16; j++) acc[j] = 0.f;
    const unsigned short* bp = xBC + (size_t)(row0 + s) * CONVDIM + BOFF;
    for (int n4 = 0; n4 < 128; n4 += 4) {
      ushort4 bu = *(const ushort4*)(bp + n4);
      float b0 = bf2f(bu.x), b1 = bf2f(bu.y), b2 = bf2f(bu.z), b3 = bf2f(bu.w);
#pragma unroll
      for (int li = 0; li < 16; li++) {
        float4 cv = *(const float4*)&Cs[(lh * 16 + li) * 132 + n4];
        acc[li] += b0 * cv.x + b1 * cv.y + b2 * cv.z + b3 * cv.w;
      }
    }
#pragma unroll
    for (int li = 0; li < 16; li++) {
      int gl = lt * 32 + lh * 16 + li;
      cbuf[((size_t)bc * 128 + gl) * 128 + s] = acc[li];
    }
  }
}

// ---------------- per-chunk raw states via MFMA ----------------
__global__ __launch_bounds__(256, 2) void k_states(
    const unsigned short* __restrict__ xBC, const float* __restrict__ dt,
    const float* __restrict__ A_log, float* __restrict__ states,
    float* __restrict__ dAsum) {
  constexpr int LP = 136;
  int id = blockIdx.x; int h = id & 63; int bc = id >> 6; int row0 = bc * CHUNK;
  int t = threadIdx.x;
  __shared__ float Acum[128];
  __shared__ float wdec[128];
  __shared__ __align__(16) unsigned short Bt[128 * LP]; // [n][l^]
  __shared__ __align__(16) unsigned short Xt[64 * LP];  // [p][l^]
  float Ah = -expf(A_log[h]);
  if (t < 128) Acum[t] = dt[(size_t)(row0 + t) * 64 + h] * Ah;
  __syncthreads();
  for (int off = 1; off < 128; off <<= 1) {
    float v = 0.f;
    bool act = (t < 128) && (t >= off);
    if (act) v = Acum[t - off];
    __syncthreads();
    if (act) Acum[t] += v;
    __syncthreads();
  }
  float Alast = Acum[127];
  if (t < 128) wdec[t] = __expf(Alast - Acum[t]);
  if (t == 0) dAsum[id] = Alast;
  __syncthreads();
  for (int i = t; i < 16 * 128; i += 256) {
    int l = i >> 4, n0 = (i & 15) * 8;
    const unsigned short* src = xBC + (size_t)(row0 + l) * CONVDIM + BOFF + n0;
    ushort4 v0 = *(const ushort4*)src;
    ushort4 v1 = *(const ushort4*)(src + 4);
    float wl = wdec[l];
    int ls = l ^ (n0 & 24);
    Bt[(n0 + 0) * LP + ls] = f2bf(bf2f(v0.x) * wl);
    Bt[(n0 + 1) * LP + ls] = f2bf(bf2f(v0.y) * wl);
    Bt[(n0 + 2) * LP + ls] = f2bf(bf2f(v0.z) * wl);
    Bt[(n0 + 3) * LP + ls] = f2bf(bf2f(v0.w) * wl);
    Bt[(n0 + 4) * LP + ls] = f2bf(bf2f(v1.x) * wl);
    Bt[(n0 + 5) * LP + ls] = f2bf(bf2f(v1.y) * wl);
    Bt[(n0 + 6) * LP + ls] = f2bf(bf2f(v1.z) * wl);
    Bt[(n0 + 7) * LP + ls] = f2bf(bf2f(v1.w) * wl);
  }
  for (int i = t; i < 8 * 128; i += 256) {
    int l = i >> 3, p0 = (i & 7) * 8;
    const unsigned short* src = xBC + (size_t)(row0 + l) * CONVDIM + h * HEADDIM + p0;
    ushort4 v0 = *(const ushort4*)src;
    ushort4 v1 = *(const ushort4*)(src + 4);
    float dl = dt[(size_t)(row0 + l) * 64 + h];
    int ls = l ^ (p0 & 24);
    Xt[(p0 + 0) * LP + ls] = f2bf(bf2f(v0.x) * dl);
    Xt[(p0 + 1) * LP + ls] = f2bf(bf2f(v0.y) * dl);
    Xt[(p0 + 2) * LP + ls] = f2bf(bf2f(v0.z) * dl);
    Xt[(p0 + 3) * LP + ls] = f2bf(bf2f(v0.w) * dl);
    Xt[(p0 + 4) * LP + ls] = f2bf(bf2f(v1.x) * dl);
    Xt[(p0 + 5) * LP + ls] = f2bf(bf2f(v1.y) * dl);
    Xt[(p0 + 6) * LP + ls] = f2bf(bf2f(v1.z) * dl);
    Xt[(p0 + 7) * LP + ls] = f2bf(bf2f(v1.w) * dl);
  }
  __syncthreads();
  int w = t >> 6, lane = t & 63;
  int lr = lane & 15, lk = (lane >> 4) * 8;
  int pp = w * 16 + lr;
  f32x4 acc[8] = {};
  for (int k0 = 0; k0 < 128; k0 += 32) {
    bf16x8 af = *(const bf16x8*)&Xt[pp * LP + ((k0 + lk) ^ (pp & 24))];
#pragma unroll
    for (int nt = 0; nt < 8; nt++) {
      int nn = nt * 16 + lr;
      bf16x8 bfr = *(const bf16x8*)&Bt[nn * LP + ((k0 + lk) ^ (nn & 24))];
      acc[nt] = __builtin_amdgcn_mfma_f32_16x16x32_bf16(af, bfr, acc[nt], 0, 0, 0);
    }
  }
  float* sp = states + (size_t)id * 8192;
  int orow = (lane >> 4) * 4, ocol = lane & 15;
#pragma unroll
  for (int nt = 0; nt < 8; nt++)
#pragma unroll
    for (int r = 0; r < 4; r++)
      sp[(w * 16 + orow + r) * 128 + nt * 16 + ocol] = acc[nt][r];
}

// ---------------- inter-chunk recurrence, 16-way split of state vector ----------------
__global__ __launch_bounds__(256) void k_scan(float* __restrict__ states,
                                              const float* __restrict__ dAsum) {
  int blk = blockIdx.x;              // (b*64+h)*16 + seg
  int seg = blk & 15, bh = blk >> 4;
  int b = bh >> 6, h = bh & 63;
  int e = seg * 512 + threadIdx.x * 2;
  float cx = 0.f, cy = 0.f;
  for (int c = 0; c < NCH; c++) {
    int bc = b * NCH + c;
    float* p = states + ((size_t)bc * 64 + h) * 8192 + e;
    float dec = __expf(dAsum[bc * 64 + h]);
    float2 raw = *(float2*)p;
    float2 cur = {cx, cy};
    *(float2*)p = cur;
    cx = cx * dec + raw.x;
    cy = cy * dec + raw.y;
  }
}

// ---------------- Y = Y_off + Y_diag + D*x via MFMA; Y in place over states ----------------
__global__ __launch_bounds__(256, 2) void k_ssd_y(
    const unsigned short* __restrict__ xBC, const float* __restrict__ dt,
    float* __restrict__ states, const float* __restrict__ cbuf,
    const float* __restrict__ A_log, const float* __restrict__ Dv) {
  constexpr int LP = 136;
  int id = blockIdx.x;
  int h = id & 63, bc = id >> 6;
  int row0 = bc * CHUNK;
  int t = threadIdx.x;
  __shared__ float Acum[128];
  __shared__ __align__(16) unsigned short LA[64 * LP];   // S (phase A), Xt (phase B)
  __shared__ __align__(16) unsigned short LB[128 * LP];  // Cexp (phase A), M (phase B)
  float Ah = -expf(A_log[h]);
  if (t < 128) Acum[t] = dt[(size_t)(row0 + t) * 64 + h] * Ah;
  __syncthreads();
  for (int off = 1; off < 128; off <<= 1) {
    float v = 0.f;
    bool act = (t < 128) && (t >= off);
    if (act) v = Acum[t - off];
    __syncthreads();
    if (act) Acum[t] += v;
    __syncthreads();
  }
  float* sp = states + (size_t)id * 8192;
  for (int i4 = t; i4 < 2048; i4 += 256) {
    int p = i4 >> 5, n0 = (i4 & 31) * 4;
    float4 v = *(const float4*)(sp + p * 128 + n0);
    ushort4 o; o.x = f2bf(v.x); o.y = f2bf(v.y); o.z = f2bf(v.z); o.w = f2bf(v.w);
    *(ushort4*)&LA[p * LP + n0] = o;
  }
  for (int i = t; i < 16 * 128; i += 256) {
    int l = i >> 4, n0 = (i & 15) * 8;
    const unsigned short* src = xBC + (size_t)(row0 + l) * CONVDIM + COFF + n0;
    ushort4 v0 = *(const ushort4*)src;
    ushort4 v1 = *(const ushort4*)(src + 4);
    float el = __expf(Acum[l]);
    ushort4 o0, o1;
    o0.x = f2bf(bf2f(v0.x) * el); o0.y = f2bf(bf2f(v0.y) * el);
    o0.z = f2bf(bf2f(v0.z) * el); o0.w = f2bf(bf2f(v0.w) * el);
    o1.x = f2bf(bf2f(v1.x) * el); o1.y = f2bf(bf2f(v1.y) * el);
    o1.z = f2bf(bf2f(v1.z) * el); o1.w = f2bf(bf2f(v1.w) * el);
    *(ushort4*)&LB[l * LP + n0] = o0;
    *(ushort4*)&LB[l * LP + n0 + 4] = o1;
  }
  __syncthreads();
  int w = t >> 6, lane = t & 63;
  int lr = lane & 15, lk = (lane >> 4) * 8;
  f32x4 acc[2][4] = {};
#pragma unroll
  for (int k0 = 0; k0 < 128; k0 += 32) {
    bf16x8 af[2], bfv[4];
#pragma unroll
    for (int mt = 0; mt < 2; mt++)
      af[mt] = *(const bf16x8*)&LB[(w * 32 + mt * 16 + lr) * LP + k0 + lk];
#pragma unroll
    for (int nt = 0; nt < 4; nt++)
      bfv[nt] = *(const bf16x8*)&LA[(nt * 16 + lr) * LP + k0 + lk];
#pragma unroll
    for (int mt = 0; mt < 2; mt++)
#pragma unroll
      for (int nt = 0; nt < 4; nt++)
        acc[mt][nt] = __builtin_amdgcn_mfma_f32_16x16x32_bf16(af[mt], bfv[nt], acc[mt][nt], 0, 0, 0);
  }
  __syncthreads();
  for (int i = t; i < 16 * 128; i += 256) {
    int l = i >> 4, s0 = (i & 15) * 8;
    const float* cbp = cbuf + ((size_t)bc * 128 + l) * 128 + s0;
    float4 c0 = *(const float4*)cbp;
    float4 c1 = *(const float4*)(cbp + 4);
    float al = Acum[l];
    ushort4 o0, o1;
    o0.x = (s0 + 0 <= l) ? f2bf(c0.x * __expf(al - Acum[s0 + 0])) : 0;
    o0.y = (s0 + 1 <= l) ? f2bf(c0.y * __expf(al - Acum[s0 + 1])) : 0;
    o0.z = (s0 + 2 <= l) ? f2bf(c0.z * __expf(al - Acum[s0 + 2])) : 0;
    o0.w = (s0 + 3 <= l) ? f2bf(c0.w * __expf(al - Acum[s0 + 3])) : 0;
    o1.x = (s0 + 4 <= l) ? f2bf(c1.x * __expf(al - Acum[s0 + 4])) : 0;
    o1.y = (s0 + 5 <= l) ? f2bf(c1.y * __expf(al - Acum[s0 + 5])) : 0;
    o1.z = (s0 + 6 <= l) ? f2bf(c1.z * __expf(al - Acum[s0 + 6])) : 0;
    o1.w = (s0 + 7 <= l) ? f2bf(c1.w * __expf(al - Acum[s0 + 7])) : 0;
    *(ushort4*)&LB[l * LP + s0] = o0;
    *(ushort4*)&LB[l * LP + s0 + 4] = o1;
  }
  for (int i = t; i < 8 * 128; i += 256) {
    int s = i >> 3, p0 = (i & 7) * 8;
    const unsigned short* src = xBC + (size_t)(row0 + s) * CONVDIM + h * HEADDIM + p0;
    ushort4 v0 = *(const ushort4*)src;
    ushort4 v1 = *(const ushort4*)(src + 4);
    float dl = dt[(size_t)(row0 + s) * 64 + h];
    int ss = s ^ (p0 & 24);
    LA[(p0 + 0) * LP + ss] = f2bf(bf2f(v0.x) * dl);
    LA[(p0 + 1) * LP + ss] = f2bf(bf2f(v0.y) * dl);
    LA[(p0 + 2) * LP + ss] = f2bf(bf2f(v0.z) * dl);
    LA[(p0 + 3) * LP + ss] = f2bf(bf2f(v0.w) * dl);
    LA[(p0 + 4) * LP + ss] = f2bf(bf2f(v1.x) * dl);
    LA[(p0 + 5) * LP + ss] = f2bf(bf2f(v1.y) * dl);
    LA[(p0 + 6) * LP + ss] = f2bf(bf2f(v1.z) * dl);
    LA[(p0 + 7) * LP + ss] = f2bf(bf2f(v1.w) * dl);
  }
  __syncthreads();
#pragma unroll
  for (int k0 = 0; k0 < 128; k0 += 32) {
    bf16x8 af[2], bfv[4];
#pragma unroll
    for (int mt = 0; mt < 2; mt++)
      af[mt] = *(const bf16x8*)&LB[(w * 32 + mt * 16 + lr) * LP + k0 + lk];
#pragma unroll
    for (int nt = 0; nt < 4; nt++) {
      int pp = nt * 16 + lr;
      bfv[nt] = *(const bf16x8*)&LA[pp * LP + ((k0 + lk) ^ (pp & 24))];
    }
#pragma unroll
    for (int mt = 0; mt < 2; mt++)
#pragma unroll
      for (int nt = 0; nt < 4; nt++)
        acc[mt][nt] = __builtin_amdgcn_mfma_f32_16x16x32_bf16(af[mt], bfv[nt], acc[mt][nt], 0, 0, 0);
  }
  float Dh = Dv[h];
  int orow = (lane >> 4) * 4, ocol = lane & 15;
#pragma unroll
  for (int mt = 0; mt < 2; mt++)
#pragma unroll
    for (int nt = 0; nt < 4; nt++) {
      int l0 = w * 32 + mt * 16 + orow;
      int p = nt * 16 + ocol;
#pragma unroll
      for (int r = 0; r < 4; r++) {
        int l = l0 + r;
        float xv = bf2f(xBC[(size_t)(row0 + l) * CONVDIM + h * HEADDIM + p]);
        sp[l * 64 + p] = acc[mt][nt][r] + Dh * xv;
      }
    }
}

// ---------------- gate (silu(z)), RMS norm, scale, -> bf16 ----------------
__global__ __launch_bounds__(256) void k_gate_rms(
    const float* __restrict__ Yst, const unsigned short* __restrict__ zx,
    const float* __restrict__ norm_w, unsigned short* __restrict__ ybf) {
  int row = blockIdx.x, t = threadIdx.x;
  int bc = row >> 7, ll = row & 127;
  float vals[16];
  float ss = 0.f;
#pragma unroll
  for (int j = 0; j < 16; j++) {
    int d = t + j * 256;
    int h = d >> 6, p = d & 63;
    float yv = Yst[(((size_t)bc * 64 + h) * 8192) + ll * 64 + p];
    float z = bf2f(zx[(size_t)row * DINP + d]);
    float g = yv * (z / (1.f + __expf(-z)));
    vals[j] = g;
    ss += g * g;
  }
#pragma unroll
  for (int off = 32; off > 0; off >>= 1) ss += __shfl_down(ss, off, 64);
  __shared__ float red[4];
  if ((t & 63) == 0) red[t >> 6] = ss;
  __syncthreads();
  float tot = red[0] + red[1] + red[2] + red[3];
  float rms = rsqrtf(tot / (float)D_SSM + 1e-5f);
#pragma unroll
  for (int j = 0; j < 16; j++) {
    int d = t + j * 256;
    ybf[(size_t)row * D_SSM + d] = f2bf(vals[j] * rms * norm_w[d]);
  }
}

// ---------------- out += out[:, ::-1, :] (in place, pairwise) ----------------
__global__ void k_flipadd(float* __restrict__ out) {
  int id = blockIdx.x * 256 + threadIdx.x;   // B * (L/2) * D_MODEL
  int d = id & 2047;
  int rem = id >> 11;
  int l = rem & 1023;
  int b = rem >> 10;
  size_t i1 = ((size_t)b * LSEQ + l) * D_MODEL + d;
  size_t i2 = ((size_t)b * LSEQ + (LSEQ - 1 - l)) * D_MODEL + d;
  float a = out[i1], c = out[i2];
  out[i1] = a + c;
  out[i2] = a + c;
}

// ---------------- launch ----------------
extern "C" void kernel_launch(void* const* d_in, const int* in_sizes, int n_in,
                              void* d_out, int out_size, void* d_ws, size_t ws_size,
                              hipStream_t stream) {
  if (ws_size < WS_NEED) return;   // fail cleanly instead of OOB-faulting
  const float* u       = (const float*)d_in[0];
  const float* W_in    = (const float*)d_in[1];
  const float* conv_w  = (const float*)d_in[2];
  const float* conv_b  = (const float*)d_in[3];
  const float* dt_bias = (const float*)d_in[4];
  const float* A_log   = (const float*)d_in[5];
  const float* Dv      = (const float*)d_in[6];
  const float* norm_w  = (const float*)d_in[7];
  const float* W_out   = (const float*)d_in[8];
  float* out = (float*)d_out;
  char* ws = (char*)d_ws;

  unsigned short* winb = (unsigned short*)(ws + OFF_WIN); // later: y bf16
  unsigned short* ub   = (unsigned short*)(ws + OFF_UB);  // later: W_out bf16
  unsigned short* zx   = (unsigned short*)(ws + OFF_ZX);
  unsigned short* xbc  = (unsigned short*)(ws + OFF_XBC);
  float* dtb  = (float*)(ws + OFF_DT);
  float* st   = (float*)(ws + OFF_ST);   // states, then Y in place
  float* cbuf = (float*)(ws + OFF_CB);
  float* dAs  = (float*)(ws + OFF_DAS);

  k_cvt_uw<<<(2097152 + 4390912 + 255) / 256, 256, 0, stream>>>(
      (const float4*)u, (ushort4*)ub, (const float4*)W_in, (ushort4*)winb);
  k_gemm_bt<true><<<(DINP / 128) * (BL / 128), 256, 0, stream>>>(ub, winb, zx, BL, DINP, D_MODEL);
  k_cvt4<<<2097152 / 256, 256, 0, stream>>>((const float4*)W_out, (ushort4*)ub, 2097152, 2097152);
  k_dt<<<BL * 64 / 256, 256, 0, stream>>>(zx, dt_bias, dtb);
  k_conv<<<(BL * (CONVDIM / 8)) / 256, 256, 0, stream>>>(zx, conv_w, conv_b, xbc);
  k_cb<<<B_SZ * NCH, 256, 0, stream>>>(xbc, cbuf);
  k_states<<<B_SZ * NCH * NHEADS, 256, 0, stream>>>(xbc, dtb, A_log, st, dAs);
  k_scan<<<B_SZ * NHEADS * 16, 256, 0, stream>>>(st, dAs);
  k_ssd_y<<<B_SZ * NCH * NHEADS, 256, 0, stream>>>(xbc, dtb, st, cbuf, A_log, Dv);
  k_gate_rms<<<BL, 256, 0, stream>>>(st, zx, norm_w, winb);
  k_gemm_bt<false><<<(D_MODEL / 128) * (BL / 128), 256, 0, stream>>>(winb, ub, out, BL, D_MODEL, D_SSM);
  k_flipadd<<<(B_SZ * (LSEQ / 2) * D_MODEL) / 256, 256, 0, stream>>>(out);
}